// Round 1
// baseline (3173.655 us; speedup 1.0000x reference)
//
#include <hip/hip_runtime.h>
#include <hip/hip_bf16.h>

// Problem constants
#define T_TOK 1024
#define HDIM  2048
#define NEXP  32
#define TOPK  4
#define CAP   256
#define FDIM  1408
#define FSDIM 5632

// GEMM tiling
#define BM 64
#define BN 64
#define BK 16

// ---------------------------------------------------------------------------
// Router: logits = x@Wr -> softmax -> top4 -> renorm; shared gate sigmoid(x@Wse);
// atomic slot assignment into per-expert lists.
// ---------------------------------------------------------------------------
__global__ __launch_bounds__(256) void router_kernel(
    const float* __restrict__ x, const float* __restrict__ Wr,
    const float* __restrict__ Wse,
    int* __restrict__ counts, int* __restrict__ slot_token,
    float* __restrict__ slot_weight, float* __restrict__ gate) {
  __shared__ float xs[HDIM];
  __shared__ float part[256];
  __shared__ float logits[NEXP];
  __shared__ float probs[NEXP];

  const int t = blockIdx.x;
  const float* xrow = x + (size_t)t * HDIM;
  for (int i = threadIdx.x; i < HDIM; i += 256) xs[i] = xrow[i];
  __syncthreads();

  // logits: thread (e = tid&31, chunk c = tid>>5) partial over 256 h's
  const int e = threadIdx.x & 31;
  const int c = threadIdx.x >> 5;
  float acc = 0.f;
  const int h0 = c * (HDIM / 8);
  for (int h = h0; h < h0 + (HDIM / 8); ++h) acc += xs[h] * Wr[h * NEXP + e];
  part[threadIdx.x] = acc;
  __syncthreads();
  if (threadIdx.x < NEXP) {
    float s = 0.f;
    #pragma unroll
    for (int cc = 0; cc < 8; ++cc) s += part[cc * 32 + threadIdx.x];
    logits[threadIdx.x] = s;
  }
  __syncthreads();

  // shared-expert gate: sigmoid(x . Wse)
  float ga = 0.f;
  for (int h = threadIdx.x; h < HDIM; h += 256) ga += xs[h] * Wse[h];
  part[threadIdx.x] = ga;
  __syncthreads();
  for (int ofs = 128; ofs > 0; ofs >>= 1) {
    if (threadIdx.x < ofs) part[threadIdx.x] += part[threadIdx.x + ofs];
    __syncthreads();
  }

  if (threadIdx.x == 0) {
    gate[t] = 1.f / (1.f + expf(-part[0]));
    float m = -1e30f;
    for (int i = 0; i < NEXP; ++i) m = fmaxf(m, logits[i]);
    float sum = 0.f;
    for (int i = 0; i < NEXP; ++i) { probs[i] = expf(logits[i] - m); sum += probs[i]; }
    const float inv = 1.f / sum;
    for (int i = 0; i < NEXP; ++i) probs[i] *= inv;
    int idx[TOPK]; float w[TOPK]; float wsum = 0.f;
    for (int k = 0; k < TOPK; ++k) {
      int bi = 0; float bv = -1.f;
      for (int i = 0; i < NEXP; ++i)
        if (probs[i] > bv) { bv = probs[i]; bi = i; }
      idx[k] = bi; w[k] = bv; wsum += bv; probs[bi] = -2.f;
    }
    const float invw = 1.f / wsum;
    for (int k = 0; k < TOPK; ++k) {
      int slot = atomicAdd(&counts[idx[k]], 1);
      if (slot < CAP) {
        slot_token[idx[k] * CAP + slot] = t;
        slot_weight[idx[k] * CAP + slot] = w[k] * invw;
      }
    }
  }
}

// ---------------------------------------------------------------------------
// S1: hs[t,f] = silu(x@Wsg)[t,f] * (x@Wsu)[t,f]   M=1024 N=5632 K=2048
// ---------------------------------------------------------------------------
__global__ __launch_bounds__(256) void s1_kernel(
    const float* __restrict__ A, const float* __restrict__ B1,
    const float* __restrict__ B2, float* __restrict__ C) {
  const int N = FSDIM, Kd = HDIM;
  __shared__ float As[BK][BM + 4];
  __shared__ float Bs1[BK][BN];
  __shared__ float Bs2[BK][BN];
  const int bn = blockIdx.x * BN;
  const int bm = blockIdx.y * BM;
  const int tid = threadIdx.x;
  const int tx = tid & 15, ty = tid >> 4;
  const int lk = tid & 15, lm = (tid >> 4) * 4;
  const int bnb = tid & 63, bkb = (tid >> 6) * 4;
  float acc1[4][4] = {}, acc2[4][4] = {};
  for (int k0 = 0; k0 < Kd; k0 += BK) {
    #pragma unroll
    for (int i = 0; i < 4; ++i)
      As[lk][lm + i] = A[(size_t)(bm + lm + i) * Kd + k0 + lk];
    #pragma unroll
    for (int i = 0; i < 4; ++i) {
      Bs1[bkb + i][bnb] = B1[(size_t)(k0 + bkb + i) * N + bn + bnb];
      Bs2[bkb + i][bnb] = B2[(size_t)(k0 + bkb + i) * N + bn + bnb];
    }
    __syncthreads();
    #pragma unroll
    for (int kk = 0; kk < BK; ++kk) {
      float a[4], b1[4], b2[4];
      #pragma unroll
      for (int i = 0; i < 4; ++i) a[i] = As[kk][ty * 4 + i];
      #pragma unroll
      for (int j = 0; j < 4; ++j) { b1[j] = Bs1[kk][tx * 4 + j]; b2[j] = Bs2[kk][tx * 4 + j]; }
      #pragma unroll
      for (int i = 0; i < 4; ++i)
        #pragma unroll
        for (int j = 0; j < 4; ++j) { acc1[i][j] += a[i] * b1[j]; acc2[i][j] += a[i] * b2[j]; }
    }
    __syncthreads();
  }
  #pragma unroll
  for (int i = 0; i < 4; ++i)
    #pragma unroll
    for (int j = 0; j < 4; ++j) {
      float g = acc1[i][j];
      float s = g / (1.f + __expf(-g));
      C[(size_t)(bm + ty * 4 + i) * N + bn + tx * 4 + j] = s * acc2[i][j];
    }
}

// ---------------------------------------------------------------------------
// S2: out[t,h] = (hs @ Wsd)[t,h] * gate[t]    M=1024 N=2048 K=5632
// ---------------------------------------------------------------------------
__global__ __launch_bounds__(256) void s2_kernel(
    const float* __restrict__ A, const float* __restrict__ B,
    const float* __restrict__ gate, float* __restrict__ out) {
  const int N = HDIM, Kd = FSDIM;
  __shared__ float As[BK][BM + 4];
  __shared__ float Bs[BK][BN];
  const int bn = blockIdx.x * BN;
  const int bm = blockIdx.y * BM;
  const int tid = threadIdx.x;
  const int tx = tid & 15, ty = tid >> 4;
  const int lk = tid & 15, lm = (tid >> 4) * 4;
  const int bnb = tid & 63, bkb = (tid >> 6) * 4;
  float acc[4][4] = {};
  for (int k0 = 0; k0 < Kd; k0 += BK) {
    #pragma unroll
    for (int i = 0; i < 4; ++i)
      As[lk][lm + i] = A[(size_t)(bm + lm + i) * Kd + k0 + lk];
    #pragma unroll
    for (int i = 0; i < 4; ++i)
      Bs[bkb + i][bnb] = B[(size_t)(k0 + bkb + i) * N + bn + bnb];
    __syncthreads();
    #pragma unroll
    for (int kk = 0; kk < BK; ++kk) {
      float a[4], b[4];
      #pragma unroll
      for (int i = 0; i < 4; ++i) a[i] = As[kk][ty * 4 + i];
      #pragma unroll
      for (int j = 0; j < 4; ++j) b[j] = Bs[kk][tx * 4 + j];
      #pragma unroll
      for (int i = 0; i < 4; ++i)
        #pragma unroll
        for (int j = 0; j < 4; ++j) acc[i][j] += a[i] * b[j];
    }
    __syncthreads();
  }
  #pragma unroll
  for (int i = 0; i < 4; ++i) {
    const float gt = gate[bm + ty * 4 + i];
    #pragma unroll
    for (int j = 0; j < 4; ++j)
      out[(size_t)(bm + ty * 4 + i) * N + bn + tx * 4 + j] = acc[i][j] * gt;
  }
}

// ---------------------------------------------------------------------------
// E1: per expert, gathered rows: he[e,m,f] = silu(x_tok@Wg[e]) * (x_tok@Wu[e])
// grid: (F/BN, CAP/BM, E)
// ---------------------------------------------------------------------------
__global__ __launch_bounds__(256) void e1_kernel(
    const float* __restrict__ x, const float* __restrict__ Wg,
    const float* __restrict__ Wu, const int* __restrict__ counts,
    const int* __restrict__ slot_token, float* __restrict__ he) {
  const int N = FDIM, Kd = HDIM;
  const int e = blockIdx.z;
  int cnt = counts[e];
  if (cnt > CAP) cnt = CAP;
  const int bm = blockIdx.y * BM;
  if (bm >= cnt) return;
  __shared__ float As[BK][BM + 4];
  __shared__ float Bs1[BK][BN];
  __shared__ float Bs2[BK][BN];
  const int bn = blockIdx.x * BN;
  const int tid = threadIdx.x;
  const int tx = tid & 15, ty = tid >> 4;
  const int lk = tid & 15, lm = (tid >> 4) * 4;
  const int bnb = tid & 63, bkb = (tid >> 6) * 4;
  const float* B1 = Wg + (size_t)e * Kd * N;
  const float* B2 = Wu + (size_t)e * Kd * N;
  int tok[4];
  #pragma unroll
  for (int i = 0; i < 4; ++i) {
    int m = bm + lm + i;
    tok[i] = (m < cnt) ? slot_token[e * CAP + m] : -1;
  }
  float acc1[4][4] = {}, acc2[4][4] = {};
  for (int k0 = 0; k0 < Kd; k0 += BK) {
    #pragma unroll
    for (int i = 0; i < 4; ++i)
      As[lk][lm + i] = (tok[i] >= 0) ? x[(size_t)tok[i] * Kd + k0 + lk] : 0.f;
    #pragma unroll
    for (int i = 0; i < 4; ++i) {
      Bs1[bkb + i][bnb] = B1[(size_t)(k0 + bkb + i) * N + bn + bnb];
      Bs2[bkb + i][bnb] = B2[(size_t)(k0 + bkb + i) * N + bn + bnb];
    }
    __syncthreads();
    #pragma unroll
    for (int kk = 0; kk < BK; ++kk) {
      float a[4], b1[4], b2[4];
      #pragma unroll
      for (int i = 0; i < 4; ++i) a[i] = As[kk][ty * 4 + i];
      #pragma unroll
      for (int j = 0; j < 4; ++j) { b1[j] = Bs1[kk][tx * 4 + j]; b2[j] = Bs2[kk][tx * 4 + j]; }
      #pragma unroll
      for (int i = 0; i < 4; ++i)
        #pragma unroll
        for (int j = 0; j < 4; ++j) { acc1[i][j] += a[i] * b1[j]; acc2[i][j] += a[i] * b2[j]; }
    }
    __syncthreads();
  }
  #pragma unroll
  for (int i = 0; i < 4; ++i) {
    const int m = bm + ty * 4 + i;
    if (m < cnt) {
      #pragma unroll
      for (int j = 0; j < 4; ++j) {
        float g = acc1[i][j];
        float s = g / (1.f + __expf(-g));
        he[((size_t)e * CAP + m) * N + bn + tx * 4 + j] = s * acc2[i][j];
      }
    }
  }
}

// ---------------------------------------------------------------------------
// E2: ye = he @ Wd[e]; out[token] += w * ye   (atomic combine)
// grid: (H/BN, CAP/BM, E)
// ---------------------------------------------------------------------------
__global__ __launch_bounds__(256) void e2_kernel(
    const float* __restrict__ he, const float* __restrict__ Wd,
    const int* __restrict__ counts, const int* __restrict__ slot_token,
    const float* __restrict__ slot_weight, float* __restrict__ out) {
  const int N = HDIM, Kd = FDIM;
  const int e = blockIdx.z;
  int cnt = counts[e];
  if (cnt > CAP) cnt = CAP;
  const int bm = blockIdx.y * BM;
  if (bm >= cnt) return;
  __shared__ float As[BK][BM + 4];
  __shared__ float Bs[BK][BN];
  const int bn = blockIdx.x * BN;
  const int tid = threadIdx.x;
  const int tx = tid & 15, ty = tid >> 4;
  const int lk = tid & 15, lm = (tid >> 4) * 4;
  const int bnb = tid & 63, bkb = (tid >> 6) * 4;
  const float* A = he + (size_t)e * CAP * Kd;
  const float* B = Wd + (size_t)e * Kd * N;
  float acc[4][4] = {};
  for (int k0 = 0; k0 < Kd; k0 += BK) {
    #pragma unroll
    for (int i = 0; i < 4; ++i) {
      int m = bm + lm + i;
      As[lk][lm + i] = (m < cnt) ? A[(size_t)m * Kd + k0 + lk] : 0.f;
    }
    #pragma unroll
    for (int i = 0; i < 4; ++i)
      Bs[bkb + i][bnb] = B[(size_t)(k0 + bkb + i) * N + bn + bnb];
    __syncthreads();
    #pragma unroll
    for (int kk = 0; kk < BK; ++kk) {
      float a[4], b[4];
      #pragma unroll
      for (int i = 0; i < 4; ++i) a[i] = As[kk][ty * 4 + i];
      #pragma unroll
      for (int j = 0; j < 4; ++j) b[j] = Bs[kk][tx * 4 + j];
      #pragma unroll
      for (int i = 0; i < 4; ++i)
        #pragma unroll
        for (int j = 0; j < 4; ++j) acc[i][j] += a[i] * b[j];
    }
    __syncthreads();
  }
  #pragma unroll
  for (int i = 0; i < 4; ++i) {
    const int m = bm + ty * 4 + i;
    if (m < cnt) {
      const int t = slot_token[e * CAP + m];
      const float w = slot_weight[e * CAP + m];
      #pragma unroll
      for (int j = 0; j < 4; ++j)
        atomicAdd(&out[(size_t)t * N + bn + tx * 4 + j], w * acc[i][j]);
    }
  }
}

// ---------------------------------------------------------------------------
extern "C" void kernel_launch(void* const* d_in, const int* in_sizes, int n_in,
                              void* d_out, int out_size, void* d_ws, size_t ws_size,
                              hipStream_t stream) {
  const float* x   = (const float*)d_in[0];
  const float* Wr  = (const float*)d_in[1];
  const float* Wg  = (const float*)d_in[2];
  const float* Wu  = (const float*)d_in[3];
  const float* Wd  = (const float*)d_in[4];
  const float* Wsg = (const float*)d_in[5];
  const float* Wsu = (const float*)d_in[6];
  const float* Wsd = (const float*)d_in[7];
  const float* Wse = (const float*)d_in[8];
  float* out = (float*)d_out;

  // workspace layout
  char* ws = (char*)d_ws;
  int*   counts      = (int*)(ws + 0);                 // 128 B (pad to 256)
  int*   slot_token  = (int*)(ws + 256);               // 32 KB
  float* slot_weight = (float*)(ws + 256 + 32768);     // 32 KB
  float* gate        = (float*)(ws + 256 + 65536);     // 4 KB
  float* hs          = (float*)(ws + 69888);           // 1024*5632*4 = 23.07 MB
  float* he          = (float*)(ws + 69888 + (size_t)T_TOK * FSDIM * 4); // 32*256*1408*4 = 46.1 MB

  hipMemsetAsync(counts, 0, 256, stream);

  router_kernel<<<dim3(T_TOK), dim3(256), 0, stream>>>(
      x, Wr, Wse, counts, slot_token, slot_weight, gate);

  s1_kernel<<<dim3(FSDIM / BN, T_TOK / BM), dim3(256), 0, stream>>>(x, Wsg, Wsu, hs);
  s2_kernel<<<dim3(HDIM / BN, T_TOK / BM), dim3(256), 0, stream>>>(hs, Wsd, gate, out);

  e1_kernel<<<dim3(FDIM / BN, CAP / BM, NEXP), dim3(256), 0, stream>>>(
      x, Wg, Wu, counts, slot_token, he);
  e2_kernel<<<dim3(HDIM / BN, CAP / BM, NEXP), dim3(256), 0, stream>>>(
      he, Wd, counts, slot_token, slot_weight, out);
}